// Round 16
// baseline (311.654 us; speedup 1.0000x reference)
//
#include <hip/hip_runtime.h>
#include <math.h>

// SNN forward, fused. Inputs f32, output f32 [2048][200].
// R16 = R15 (fp8 weights, 4 waves/SIMD, 279us) + sched_barrier(0) fences
// around each layer's weight-load nest: stops the compiler hoisting next-layer
// weight loads above current-layer last uses (the 4 boundary spill events that
// produced WRITE_SIZE 13.4MB). No other changes.

#define T_N 150
#define DIN 20
#define H 256
#define NOUT 200
#define NMT 10
#define CST 20             // sc col stride (f32): 16 rows + 4 pad
#define SCB 5120           // sc size (f32) = 256 cols * CST
#define XAP 24             // xa row stride (bf16 shorts) = BW dwords
#define BW 12              // bits row stride (dwords)
#define BITN (160 * BW + 8)

// d_ws layout: [0,5120) shorts = bf16 W1; then fp8 bytes W2,W3,W4,Wo
#define N_W1 5120
#define F8_W2 0
#define F8_W3 65536
#define F8_W4 131072
#define F8_WO 196608
#define F8_TOT 247808

typedef short s16x8 __attribute__((ext_vector_type(8)));
typedef float f32x4 __attribute__((ext_vector_type(4)));
typedef unsigned int u32x4 __attribute__((ext_vector_type(4)));

__device__ __forceinline__ unsigned short f2bf(float f) {
  union { float f; unsigned int i; } v; v.f = f;
  unsigned int r = v.i + 0x7FFFu + ((v.i >> 16) & 1u);
  return (unsigned short)(r >> 16);
}

// f32 -> OCP e4m3 (RNE, handles subnormals; inputs |f| <= 0.25, no sat needed)
__device__ __forceinline__ unsigned char f2e4m3(float f) {
  union { float f; unsigned u; } v; v.f = f;
  unsigned s = (v.u >> 24) & 0x80u;
  unsigned mag = v.u & 0x7FFFFFFFu;
  if (mag == 0) return (unsigned char)s;
  int e = (int)(mag >> 23) - 127;
  unsigned man = mag & 0x7FFFFFu;
  unsigned q;
  if (e >= -6) {
    unsigned r = man + 0x7FFFFu + ((man >> 20) & 1u);
    if (r >= 0x800000u) { e += 1; r -= 0x800000u; }
    q = ((unsigned)(e + 7) << 3) | (r >> 20);
  } else {
    unsigned mant = 0x800000u | man;
    int sh = 14 - e;
    if (sh > 31) q = 0;
    else {
      unsigned fl = mant >> sh;
      unsigned rem = mant & ((1u << sh) - 1u);
      unsigned half = 1u << (sh - 1);
      q = fl + ((rem > half || (rem == half && (fl & 1))) ? 1u : 0u);
    }
  }
  return (unsigned char)(s | q);
}

__global__ void cvt_weights(const float* __restrict__ W1, const float* __restrict__ W2,
                            const float* __restrict__ W3, const float* __restrict__ W4,
                            const float* __restrict__ Wo, unsigned short* __restrict__ ws) {
  int idx = blockIdx.x * blockDim.x + threadIdx.x;
  int stride = gridDim.x * blockDim.x;
  for (int i = idx; i < N_W1; i += stride) ws[i] = f2bf(W1[i]);
  unsigned char* f8 = (unsigned char*)(ws + N_W1);
  for (int i = idx; i < F8_TOT; i += stride) {
    float v;
    if (i < F8_W3)      v = W2[i - F8_W2];
    else if (i < F8_W4) v = W3[i - F8_W3];
    else if (i < F8_WO) v = W4[i - F8_W4];
    else                v = Wo[i - F8_WO];
    f8[i] = f2e4m3(v);
  }
}

// expand 8 spike bits -> 8 fp8 e4m3 bytes (0x00 / 0x38) packed in a long.
__device__ __forceinline__ long expand8_f8(unsigned t) {
  unsigned lo = ((t & 0xFu) * 0x204081u) & 0x01010101u;
  unsigned hi = ((t >> 4) * 0x204081u) & 0x01010101u;
  lo *= 0x38u; hi *= 0x38u;
  union { unsigned u[2]; long l; } cv; cv.u[0] = lo; cv.u[1] = hi;
  return cv.l;
}

__global__ __launch_bounds__(256, 4) void snn_fused(
    const float* __restrict__ x,             // [2048][150][20] f32
    const unsigned short* __restrict__ wsb,  // d_ws: bf16 W1 + fp8 W2..Wo
    const float* __restrict__ b1,            // [256] f32
    const float* __restrict__ b2,
    const float* __restrict__ b3,
    const float* __restrict__ b4,
    float* __restrict__ out)                 // [2048][200] f32
{
  __shared__ float sc[SCB];                  // 20480 B: col-major C scratch
  __shared__ unsigned int ubits[2][BITN];    // 15424 B: spike bits, ping-pong
                                             // total 35904 B -> 4 blocks/CU

  const int tid  = threadIdx.x;
  const int lane = tid & 63;
  const int wave = tid >> 6;    // 0..3
  const int c16  = lane & 15;
  const int quad = lane >> 4;
  const int shq  = quad * 8;
  const int bidx = blockIdx.x;
  const int colw = 64 * wave;   // wave owns cols [64w, 64w+64)
  const int cb   = colw + c16;

  const unsigned char* f8 = (const unsigned char*)(wsb + N_W1);
  unsigned short* xa = (unsigned short*)&ubits[1][0];

  auto store_c = [&](f32x4* c) {
    #pragma unroll
    for (int i = 0; i < 4; ++i)
      *(f32x4*)&sc[(cb + 16 * i) * CST + quad * 4] = c[i];
  };

  // fused membrane scan: 64 lanes own the wave's 64 cols (wave-local sc)
  auto scan_tile = [&](int mt, float& m, unsigned int* wb) {
    const f32x4* vp = (const f32x4*)&sc[(colw + lane) * CST];
    f32x4 v[4];
    #pragma unroll
    for (int j = 0; j < 4; ++j) v[j] = vp[j];
    unsigned long long keep = 0ull;
    #pragma unroll
    for (int r = 0; r < 16; ++r) {
      int t = mt * 16 + r;
      if (t < T_N) {  // block-uniform
        float inp = v[r >> 2][r & 3];
        float sel = (m > 1.0f) ? (inp - 1.0f) : inp;
        m = 0.9f * m + sel;
        unsigned long long msk = __ballot(m > 1.0f);
        if (lane == r) keep = msk;
      }
    }
    if (lane < 16)
      *(unsigned long long*)&wb[(mt * 16 + lane) * BW + 2 * wave] = keep;
  };

  auto load_masks = [&](const unsigned int* rb, int mt, unsigned int* rm) {
    const unsigned int* bp = &rb[(mt * 16 + c16) * BW];
    u32x4 a = *(const u32x4*)bp;
    u32x4 b = *(const u32x4*)(bp + 4);
    rm[0] = a[0]; rm[1] = a[1]; rm[2] = a[2]; rm[3] = a[3];
    rm[4] = b[0]; rm[5] = b[1]; rm[6] = b[2]; rm[7] = b[3];
  };

  // ---- init: zero both bits buffers; stage x as bf16 into xa (=ubits[1]) ----
  for (int i = tid; i < 2 * BITN; i += 256) ((unsigned int*)ubits)[i] = 0;
  __syncthreads();
  {
    const float* xb = x + (size_t)bidx * (T_N * DIN);
    for (int i = tid; i < T_N * DIN; i += 256) {
      int t = i / DIN, j = i - t * DIN;
      xa[t * XAP + j] = f2bf(xb[i]);
    }
  }

  // ---- layer 1 (bf16): x @ W1^T (K=20 pad 32) -> ubits[0]; barrier-free ----
  {
    s16x8 w1f[4];
    #pragma unroll
    for (int i = 0; i < 4; ++i) {
      int n = cb + 16 * i;
      #pragma unroll
      for (int j = 0; j < 8; ++j) {
        int k = shq + j;
        w1f[i][j] = (k < DIN) ? (short)wsb[n * DIN + k] : (short)0;
      }
      asm volatile("" : "+v"(w1f[i]));
    }
    float bc[4];
    #pragma unroll
    for (int i = 0; i < 4; ++i) bc[i] = b1[cb + 16 * i];
    float m = 0.0f;
    __syncthreads();  // xa staged
    for (int mt = 0; mt < NMT; ++mt) {
      const s16x8 a1 = *(const s16x8*)&xa[(mt * 16 + c16) * XAP + shq];
      f32x4 c[4];
      #pragma unroll
      for (int i = 0; i < 4; ++i) { f32x4 z = {bc[i], bc[i], bc[i], bc[i]}; c[i] = z; }
      #pragma unroll
      for (int i = 0; i < 4; ++i)
        c[i] = __builtin_amdgcn_mfma_f32_16x16x32_bf16(a1, w1f[i], c[i], 0, 0, 0);
      if (mt > 0) scan_tile(mt - 1, m, ubits[0]);
      store_c(c);
    }
    scan_tile(9, m, ubits[0]);
  }
  __syncthreads();  // bits[0] complete (xa dead from here)

  // ---- layers 2..4 (fp8 weights): barrier-free, bits ping-pong ----
  const float* bsl[3] = {b2, b3, b4};
  const int wofs[3] = {F8_W2, F8_W3, F8_W4};
  for (int l = 0; l < 3; ++l) {
    const unsigned char* wl = f8 + wofs[l];
    const int rp = l & 1, wp = rp ^ 1;
    // fence: next-layer weight loads must not hoist above prior-layer uses
    __builtin_amdgcn_sched_barrier(0);
    long wf[4][8];
    #pragma unroll
    for (int i = 0; i < 4; ++i) {
      int n = cb + 16 * i;
      #pragma unroll
      for (int ks = 0; ks < 8; ++ks) {
        wf[i][ks] = *(const long*)(wl + n * H + ks * 32 + shq);
        asm volatile("" : "+v"(wf[i][ks]));
      }
    }
    __builtin_amdgcn_sched_barrier(0);
    float bc[4];
    #pragma unroll
    for (int i = 0; i < 4; ++i) bc[i] = bsl[l][cb + 16 * i];
    float m = 0.0f;
    for (int mt = 0; mt < NMT; ++mt) {
      unsigned int rm[8];
      load_masks(ubits[rp], mt, rm);
      f32x4 c[4];
      #pragma unroll
      for (int i = 0; i < 4; ++i) { f32x4 z = {bc[i], bc[i], bc[i], bc[i]}; c[i] = z; }
      #pragma unroll
      for (int ks = 0; ks < 8; ++ks) {
        long a = expand8_f8((rm[ks] >> shq) & 0xFFu);
        #pragma unroll
        for (int i = 0; i < 4; ++i)
          c[i] = __builtin_amdgcn_mfma_f32_16x16x32_fp8_fp8(a, wf[i][ks], c[i], 0, 0, 0);
      }
      if (mt > 0) scan_tile(mt - 1, m, ubits[wp]);
      store_c(c);
    }
    scan_tile(9, m, ubits[wp]);
    __syncthreads();  // bits[wp] complete
  }

  // ---- output layer (fp8, reads ubits[1]): GEMM + mo-scan + softmax ----
  {
    __builtin_amdgcn_sched_barrier(0);
    long wo[4][8];
    #pragma unroll
    for (int i = 0; i < 4; ++i) {
      int n = cb + 16 * i;
      bool valid = (n < NOUT);
      #pragma unroll
      for (int ks = 0; ks < 8; ++ks) {
        wo[i][ks] = valid ? *(const long*)(f8 + F8_WO + n * H + ks * 32 + shq) : 0L;
        asm volatile("" : "+v"(wo[i][ks]));
      }
    }
    __builtin_amdgcn_sched_barrier(0);

    float mo = 0.0f;
    float a0 = 0.f, a1 = 0.f, a2 = 0.f, a3 = 0.f;

    auto moscan = [&](int mt) {
      if (tid < 208) {
        f32x4* vp = (f32x4*)&sc[tid * CST];
        f32x4 v[4];
        #pragma unroll
        for (int j = 0; j < 4; ++j) v[j] = vp[j];
        #pragma unroll
        for (int r = 0; r < 16; ++r) {
          int t = mt * 16 + r;
          if (t < T_N) {
            float reset = (mo > 1.0f) ? 1.0f : 0.0f;
            mo = 0.9f * mo + v[r >> 2][r & 3] - reset;
            v[r >> 2][r & 3] = mo;
          }
        }
        #pragma unroll
        for (int j = 0; j < 4; ++j) vp[j] = v[j];
      }
    };
    auto softmax_t = [&](int mt) {
      #pragma unroll
      for (int rr = 0; rr < 4; ++rr) {
        int r = 4 * wave + rr;
        int t = mt * 16 + r;
        if (t > 50 && t < T_N) {        // wave-uniform
          const float* p = &sc[r];
          float v0 = p[lane * CST];
          float v1 = p[(64 + lane) * CST];
          float v2 = p[(128 + lane) * CST];
          bool has3 = (lane < 8);
          float v3 = has3 ? p[(192 + lane) * CST] : -INFINITY;
          float mx = fmaxf(fmaxf(v0, v1), fmaxf(v2, v3));
          #pragma unroll
          for (int d = 32; d >= 1; d >>= 1) mx = fmaxf(mx, __shfl_xor(mx, d));
          float e0 = __expf(v0 - mx), e1 = __expf(v1 - mx), e2 = __expf(v2 - mx);
          float e3 = has3 ? __expf(v3 - mx) : 0.0f;
          float s = e0 + e1 + e2 + e3;
          #pragma unroll
          for (int d = 32; d >= 1; d >>= 1) s += __shfl_xor(s, d);
          float inv = 1.0f / s;
          a0 += e0 * inv; a1 += e1 * inv; a2 += e2 * inv; a3 += e3 * inv;
        }
      }
    };

    for (int mt = 0; mt < NMT; ++mt) {
      unsigned int rm[8];
      load_masks(ubits[1], mt, rm);
      f32x4 c[4];
      #pragma unroll
      for (int i = 0; i < 4; ++i) { f32x4 z = {0.f, 0.f, 0.f, 0.f}; c[i] = z; }
      #pragma unroll
      for (int ks = 0; ks < 8; ++ks) {
        long a = expand8_f8((rm[ks] >> shq) & 0xFFu);
        #pragma unroll
        for (int i = 0; i < 4; ++i)
          c[i] = __builtin_amdgcn_mfma_f32_16x16x32_fp8_fp8(a, wo[i][ks], c[i], 0, 0, 0);
      }
      __syncthreads();              // prior softmax done reading sc
      store_c(c);
      moscan(mt);                   // wave-local after wave-local store
      __syncthreads();              // membranes visible to all waves
      softmax_t(mt);
    }
    __syncthreads();

    // merge 4 per-wave accumulators via sc, store f32
    sc[wave * 260 + lane]       = a0;
    sc[wave * 260 + 64 + lane]  = a1;
    sc[wave * 260 + 128 + lane] = a2;
    if (lane < 8) sc[wave * 260 + 192 + lane] = a3;
    __syncthreads();
    if (tid < NOUT) {
      float v = sc[tid] + sc[260 + tid] + sc[520 + tid] + sc[780 + tid];
      out[(size_t)bidx * NOUT + tid] = v;
    }
  }
}

extern "C" void kernel_launch(void* const* d_in, const int* in_sizes, int n_in,
                              void* d_out, int out_size, void* d_ws, size_t ws_size,
                              hipStream_t stream) {
  (void)in_sizes; (void)n_in; (void)ws_size; (void)out_size;
  unsigned short* wsb = (unsigned short*)d_ws;
  cvt_weights<<<256, 256, 0, stream>>>(
      (const float*)d_in[1], (const float*)d_in[3], (const float*)d_in[5],
      (const float*)d_in[7], (const float*)d_in[9], wsb);
  snn_fused<<<2048, 256, 0, stream>>>(
      (const float*)d_in[0], wsb,
      (const float*)d_in[2], (const float*)d_in[4],
      (const float*)d_in[6], (const float*)d_in[8],
      (float*)d_out);
}

// Round 17
// 310.998 us; speedup vs baseline: 1.0021x; 1.0021x over previous
//
#include <hip/hip_runtime.h>
#include <math.h>

// SNN forward, fused. Inputs f32, output f32 [2048][200].
// R17 = R16 (fp8 weights, 4 waves/SIMD) + live-range shaving to fit the
// 128-reg/wave budget of launch_bounds(256,4) exactly (kill compiler scratch:
// WRITE_SIZE 12.7MB -> 1.6MB): scan/moscan process rows in two halves
// (peak v-regs 16->8), mask dwords consumed in two halves (8->4).

#define T_N 150
#define DIN 20
#define H 256
#define NOUT 200
#define NMT 10
#define CST 20             // sc col stride (f32): 16 rows + 4 pad
#define SCB 5120           // sc size (f32) = 256 cols * CST
#define XAP 24             // xa row stride (bf16 shorts) = BW dwords
#define BW 12              // bits row stride (dwords)
#define BITN (160 * BW + 8)

// d_ws layout: [0,5120) shorts = bf16 W1; then fp8 bytes W2,W3,W4,Wo
#define N_W1 5120
#define F8_W2 0
#define F8_W3 65536
#define F8_W4 131072
#define F8_WO 196608
#define F8_TOT 247808

typedef short s16x8 __attribute__((ext_vector_type(8)));
typedef float f32x4 __attribute__((ext_vector_type(4)));
typedef unsigned int u32x4 __attribute__((ext_vector_type(4)));

__device__ __forceinline__ unsigned short f2bf(float f) {
  union { float f; unsigned int i; } v; v.f = f;
  unsigned int r = v.i + 0x7FFFu + ((v.i >> 16) & 1u);
  return (unsigned short)(r >> 16);
}

// f32 -> OCP e4m3 (RNE, handles subnormals; inputs |f| <= 0.25, no sat needed)
__device__ __forceinline__ unsigned char f2e4m3(float f) {
  union { float f; unsigned u; } v; v.f = f;
  unsigned s = (v.u >> 24) & 0x80u;
  unsigned mag = v.u & 0x7FFFFFFFu;
  if (mag == 0) return (unsigned char)s;
  int e = (int)(mag >> 23) - 127;
  unsigned man = mag & 0x7FFFFFu;
  unsigned q;
  if (e >= -6) {
    unsigned r = man + 0x7FFFFu + ((man >> 20) & 1u);
    if (r >= 0x800000u) { e += 1; r -= 0x800000u; }
    q = ((unsigned)(e + 7) << 3) | (r >> 20);
  } else {
    unsigned mant = 0x800000u | man;
    int sh = 14 - e;
    if (sh > 31) q = 0;
    else {
      unsigned fl = mant >> sh;
      unsigned rem = mant & ((1u << sh) - 1u);
      unsigned half = 1u << (sh - 1);
      q = fl + ((rem > half || (rem == half && (fl & 1))) ? 1u : 0u);
    }
  }
  return (unsigned char)(s | q);
}

__global__ void cvt_weights(const float* __restrict__ W1, const float* __restrict__ W2,
                            const float* __restrict__ W3, const float* __restrict__ W4,
                            const float* __restrict__ Wo, unsigned short* __restrict__ ws) {
  int idx = blockIdx.x * blockDim.x + threadIdx.x;
  int stride = gridDim.x * blockDim.x;
  for (int i = idx; i < N_W1; i += stride) ws[i] = f2bf(W1[i]);
  unsigned char* f8 = (unsigned char*)(ws + N_W1);
  for (int i = idx; i < F8_TOT; i += stride) {
    float v;
    if (i < F8_W3)      v = W2[i - F8_W2];
    else if (i < F8_W4) v = W3[i - F8_W3];
    else if (i < F8_WO) v = W4[i - F8_W4];
    else                v = Wo[i - F8_WO];
    f8[i] = f2e4m3(v);
  }
}

// expand 8 spike bits -> 8 fp8 e4m3 bytes (0x00 / 0x38) packed in a long.
__device__ __forceinline__ long expand8_f8(unsigned t) {
  unsigned lo = ((t & 0xFu) * 0x204081u) & 0x01010101u;
  unsigned hi = ((t >> 4) * 0x204081u) & 0x01010101u;
  lo *= 0x38u; hi *= 0x38u;
  union { unsigned u[2]; long l; } cv; cv.u[0] = lo; cv.u[1] = hi;
  return cv.l;
}

__global__ __launch_bounds__(256, 4) void snn_fused(
    const float* __restrict__ x,             // [2048][150][20] f32
    const unsigned short* __restrict__ wsb,  // d_ws: bf16 W1 + fp8 W2..Wo
    const float* __restrict__ b1,            // [256] f32
    const float* __restrict__ b2,
    const float* __restrict__ b3,
    const float* __restrict__ b4,
    float* __restrict__ out)                 // [2048][200] f32
{
  __shared__ float sc[SCB];                  // 20480 B: col-major C scratch
  __shared__ unsigned int ubits[2][BITN];    // 15424 B: spike bits, ping-pong
                                             // total 35904 B -> 4 blocks/CU

  const int tid  = threadIdx.x;
  const int lane = tid & 63;
  const int wave = tid >> 6;    // 0..3
  const int c16  = lane & 15;
  const int quad = lane >> 4;
  const int shq  = quad * 8;
  const int bidx = blockIdx.x;
  const int colw = 64 * wave;   // wave owns cols [64w, 64w+64)
  const int cb   = colw + c16;

  const unsigned char* f8 = (const unsigned char*)(wsb + N_W1);
  unsigned short* xa = (unsigned short*)&ubits[1][0];

  auto store_c = [&](f32x4* c) {
    #pragma unroll
    for (int i = 0; i < 4; ++i)
      *(f32x4*)&sc[(cb + 16 * i) * CST + quad * 4] = c[i];
  };

  // fused membrane scan, two-half form (peak live v-regs = 8 not 16).
  // 64 lanes own the wave's 64 cols (wave-local sc).
  auto scan_tile = [&](int mt, float& m, unsigned int* wb) {
    const f32x4* vp = (const f32x4*)&sc[(colw + lane) * CST];
    unsigned long long keep = 0ull;
    #pragma unroll
    for (int h = 0; h < 2; ++h) {
      f32x4 v0 = vp[2 * h], v1 = vp[2 * h + 1];
      #pragma unroll
      for (int rr = 0; rr < 8; ++rr) {
        int r = 8 * h + rr;
        int t = mt * 16 + r;
        if (t < T_N) {  // block-uniform
          float inp = (rr < 4) ? v0[rr & 3] : v1[rr & 3];
          float sel = (m > 1.0f) ? (inp - 1.0f) : inp;
          m = 0.9f * m + sel;
          unsigned long long msk = __ballot(m > 1.0f);
          if (lane == r) keep = msk;
        }
      }
    }
    if (lane < 16)
      *(unsigned long long*)&wb[(mt * 16 + lane) * BW + 2 * wave] = keep;
  };

  // ---- init: zero both bits buffers; stage x as bf16 into xa (=ubits[1]) ----
  for (int i = tid; i < 2 * BITN; i += 256) ((unsigned int*)ubits)[i] = 0;
  __syncthreads();
  {
    const float* xb = x + (size_t)bidx * (T_N * DIN);
    for (int i = tid; i < T_N * DIN; i += 256) {
      int t = i / DIN, j = i - t * DIN;
      xa[t * XAP + j] = f2bf(xb[i]);
    }
  }

  // ---- layer 1 (bf16): x @ W1^T (K=20 pad 32) -> ubits[0]; barrier-free ----
  {
    s16x8 w1f[4];
    #pragma unroll
    for (int i = 0; i < 4; ++i) {
      int n = cb + 16 * i;
      #pragma unroll
      for (int j = 0; j < 8; ++j) {
        int k = shq + j;
        w1f[i][j] = (k < DIN) ? (short)wsb[n * DIN + k] : (short)0;
      }
      asm volatile("" : "+v"(w1f[i]));
    }
    float bc[4];
    #pragma unroll
    for (int i = 0; i < 4; ++i) bc[i] = b1[cb + 16 * i];
    float m = 0.0f;
    __syncthreads();  // xa staged
    for (int mt = 0; mt < NMT; ++mt) {
      const s16x8 a1 = *(const s16x8*)&xa[(mt * 16 + c16) * XAP + shq];
      f32x4 c[4];
      #pragma unroll
      for (int i = 0; i < 4; ++i) { f32x4 z = {bc[i], bc[i], bc[i], bc[i]}; c[i] = z; }
      #pragma unroll
      for (int i = 0; i < 4; ++i)
        c[i] = __builtin_amdgcn_mfma_f32_16x16x32_bf16(a1, w1f[i], c[i], 0, 0, 0);
      if (mt > 0) scan_tile(mt - 1, m, ubits[0]);
      store_c(c);
    }
    scan_tile(9, m, ubits[0]);
  }
  __syncthreads();  // bits[0] complete (xa dead from here)

  // ---- layers 2..4 (fp8 weights): barrier-free, bits ping-pong ----
  const float* bsl[3] = {b2, b3, b4};
  const int wofs[3] = {F8_W2, F8_W3, F8_W4};
  for (int l = 0; l < 3; ++l) {
    const unsigned char* wl = f8 + wofs[l];
    const int rp = l & 1, wp = rp ^ 1;
    __builtin_amdgcn_sched_barrier(0);
    long wf[4][8];
    #pragma unroll
    for (int i = 0; i < 4; ++i) {
      int n = cb + 16 * i;
      #pragma unroll
      for (int ks = 0; ks < 8; ++ks) {
        wf[i][ks] = *(const long*)(wl + n * H + ks * 32 + shq);
        asm volatile("" : "+v"(wf[i][ks]));
      }
    }
    __builtin_amdgcn_sched_barrier(0);
    float bc[4];
    #pragma unroll
    for (int i = 0; i < 4; ++i) bc[i] = bsl[l][cb + 16 * i];
    float m = 0.0f;
    for (int mt = 0; mt < NMT; ++mt) {
      const unsigned int* bp = &ubits[rp][(mt * 16 + c16) * BW];
      f32x4 c[4];
      #pragma unroll
      for (int i = 0; i < 4; ++i) { f32x4 z = {bc[i], bc[i], bc[i], bc[i]}; c[i] = z; }
      // masks consumed in two halves (live mask regs 8 -> 4)
      #pragma unroll
      for (int h = 0; h < 2; ++h) {
        u32x4 rm = *(const u32x4*)(bp + 4 * h);
        #pragma unroll
        for (int kk = 0; kk < 4; ++kk) {
          long a = expand8_f8((rm[kk] >> shq) & 0xFFu);
          int ks = 4 * h + kk;
          #pragma unroll
          for (int i = 0; i < 4; ++i)
            c[i] = __builtin_amdgcn_mfma_f32_16x16x32_fp8_fp8(a, wf[i][ks], c[i], 0, 0, 0);
        }
      }
      if (mt > 0) scan_tile(mt - 1, m, ubits[wp]);
      store_c(c);
    }
    scan_tile(9, m, ubits[wp]);
    __syncthreads();  // bits[wp] complete
  }

  // ---- output layer (fp8, reads ubits[1]): GEMM + mo-scan + softmax ----
  {
    __builtin_amdgcn_sched_barrier(0);
    long wo[4][8];
    #pragma unroll
    for (int i = 0; i < 4; ++i) {
      int n = cb + 16 * i;
      bool valid = (n < NOUT);
      #pragma unroll
      for (int ks = 0; ks < 8; ++ks) {
        wo[i][ks] = valid ? *(const long*)(f8 + F8_WO + n * H + ks * 32 + shq) : 0L;
        asm volatile("" : "+v"(wo[i][ks]));
      }
    }
    __builtin_amdgcn_sched_barrier(0);

    float mo = 0.0f;
    float a0 = 0.f, a1 = 0.f, a2 = 0.f, a3 = 0.f;

    auto moscan = [&](int mt) {
      if (tid < 208) {
        f32x4* vp = (f32x4*)&sc[tid * CST];
        #pragma unroll
        for (int h = 0; h < 2; ++h) {
          f32x4 v0 = vp[2 * h], v1 = vp[2 * h + 1];
          #pragma unroll
          for (int rr = 0; rr < 8; ++rr) {
            int r = 8 * h + rr;
            int t = mt * 16 + r;
            if (t < T_N) {
              float inp = (rr < 4) ? v0[rr & 3] : v1[rr & 3];
              float reset = (mo > 1.0f) ? 1.0f : 0.0f;
              mo = 0.9f * mo + inp - reset;
              if (rr < 4) v0[rr & 3] = mo; else v1[rr & 3] = mo;
            }
          }
          vp[2 * h] = v0; vp[2 * h + 1] = v1;
        }
      }
    };
    auto softmax_t = [&](int mt) {
      #pragma unroll
      for (int rr = 0; rr < 4; ++rr) {
        int r = 4 * wave + rr;
        int t = mt * 16 + r;
        if (t > 50 && t < T_N) {        // wave-uniform
          const float* p = &sc[r];
          float v0 = p[lane * CST];
          float v1 = p[(64 + lane) * CST];
          float v2 = p[(128 + lane) * CST];
          bool has3 = (lane < 8);
          float v3 = has3 ? p[(192 + lane) * CST] : -INFINITY;
          float mx = fmaxf(fmaxf(v0, v1), fmaxf(v2, v3));
          #pragma unroll
          for (int d = 32; d >= 1; d >>= 1) mx = fmaxf(mx, __shfl_xor(mx, d));
          float e0 = __expf(v0 - mx), e1 = __expf(v1 - mx), e2 = __expf(v2 - mx);
          float e3 = has3 ? __expf(v3 - mx) : 0.0f;
          float s = e0 + e1 + e2 + e3;
          #pragma unroll
          for (int d = 32; d >= 1; d >>= 1) s += __shfl_xor(s, d);
          float inv = 1.0f / s;
          a0 += e0 * inv; a1 += e1 * inv; a2 += e2 * inv; a3 += e3 * inv;
        }
      }
    };

    for (int mt = 0; mt < NMT; ++mt) {
      const unsigned int* bp = &ubits[1][(mt * 16 + c16) * BW];
      f32x4 c[4];
      #pragma unroll
      for (int i = 0; i < 4; ++i) { f32x4 z = {0.f, 0.f, 0.f, 0.f}; c[i] = z; }
      #pragma unroll
      for (int h = 0; h < 2; ++h) {
        u32x4 rm = *(const u32x4*)(bp + 4 * h);
        #pragma unroll
        for (int kk = 0; kk < 4; ++kk) {
          long a = expand8_f8((rm[kk] >> shq) & 0xFFu);
          int ks = 4 * h + kk;
          #pragma unroll
          for (int i = 0; i < 4; ++i)
            c[i] = __builtin_amdgcn_mfma_f32_16x16x32_fp8_fp8(a, wo[i][ks], c[i], 0, 0, 0);
        }
      }
      __syncthreads();              // prior softmax done reading sc
      store_c(c);
      moscan(mt);                   // wave-local after wave-local store
      __syncthreads();              // membranes visible to all waves
      softmax_t(mt);
    }
    __syncthreads();

    // merge 4 per-wave accumulators via sc, store f32
    sc[wave * 260 + lane]       = a0;
    sc[wave * 260 + 64 + lane]  = a1;
    sc[wave * 260 + 128 + lane] = a2;
    if (lane < 8) sc[wave * 260 + 192 + lane] = a3;
    __syncthreads();
    if (tid < NOUT) {
      float v = sc[tid] + sc[260 + tid] + sc[520 + tid] + sc[780 + tid];
      out[(size_t)bidx * NOUT + tid] = v;
    }
  }
}

extern "C" void kernel_launch(void* const* d_in, const int* in_sizes, int n_in,
                              void* d_out, int out_size, void* d_ws, size_t ws_size,
                              hipStream_t stream) {
  (void)in_sizes; (void)n_in; (void)ws_size; (void)out_size;
  unsigned short* wsb = (unsigned short*)d_ws;
  cvt_weights<<<256, 256, 0, stream>>>(
      (const float*)d_in[1], (const float*)d_in[3], (const float*)d_in[5],
      (const float*)d_in[7], (const float*)d_in[9], wsb);
  snn_fused<<<2048, 256, 0, stream>>>(
      (const float*)d_in[0], wsb,
      (const float*)d_in[2], (const float*)d_in[4],
      (const float*)d_in[6], (const float*)d_in[8],
      (float*)d_out);
}

// Round 18
// 309.468 us; speedup vs baseline: 1.0071x; 1.0049x over previous
//
#include <hip/hip_runtime.h>
#include <math.h>

// SNN forward, fused. Inputs f32, output f32 [2048][200].
// R18 = R17 (fp8 weights, 4 waves/SIMD, bench 311us) + LDS lookup table for
// the spike->fp8 A-fragment expansion: 256-entry x 8B LUT (built once/block)
// replaces the ~9-VALU mul-spread sequence with bfe+lshl+ds_read_b64.
// Sparse masks => many 0x00 bytes => same-address broadcast (free).
// LDS 35.9 -> 37.9 KB, still 4 blocks/CU.

#define T_N 150
#define DIN 20
#define H 256
#define NOUT 200
#define NMT 10
#define CST 20             // sc col stride (f32): 16 rows + 4 pad
#define SCB 5120           // sc size (f32) = 256 cols * CST
#define XAP 24             // xa row stride (bf16 shorts) = BW dwords
#define BW 12              // bits row stride (dwords)
#define BITN (160 * BW + 8)

// d_ws layout: [0,5120) shorts = bf16 W1; then fp8 bytes W2,W3,W4,Wo
#define N_W1 5120
#define F8_W2 0
#define F8_W3 65536
#define F8_W4 131072
#define F8_WO 196608
#define F8_TOT 247808

typedef short s16x8 __attribute__((ext_vector_type(8)));
typedef float f32x4 __attribute__((ext_vector_type(4)));
typedef unsigned int u32x4 __attribute__((ext_vector_type(4)));

__device__ __forceinline__ unsigned short f2bf(float f) {
  union { float f; unsigned int i; } v; v.f = f;
  unsigned int r = v.i + 0x7FFFu + ((v.i >> 16) & 1u);
  return (unsigned short)(r >> 16);
}

// f32 -> OCP e4m3 (RNE, handles subnormals; inputs |f| <= 0.25, no sat needed)
__device__ __forceinline__ unsigned char f2e4m3(float f) {
  union { float f; unsigned u; } v; v.f = f;
  unsigned s = (v.u >> 24) & 0x80u;
  unsigned mag = v.u & 0x7FFFFFFFu;
  if (mag == 0) return (unsigned char)s;
  int e = (int)(mag >> 23) - 127;
  unsigned man = mag & 0x7FFFFFu;
  unsigned q;
  if (e >= -6) {
    unsigned r = man + 0x7FFFFu + ((man >> 20) & 1u);
    if (r >= 0x800000u) { e += 1; r -= 0x800000u; }
    q = ((unsigned)(e + 7) << 3) | (r >> 20);
  } else {
    unsigned mant = 0x800000u | man;
    int sh = 14 - e;
    if (sh > 31) q = 0;
    else {
      unsigned fl = mant >> sh;
      unsigned rem = mant & ((1u << sh) - 1u);
      unsigned half = 1u << (sh - 1);
      q = fl + ((rem > half || (rem == half && (fl & 1))) ? 1u : 0u);
    }
  }
  return (unsigned char)(s | q);
}

__global__ void cvt_weights(const float* __restrict__ W1, const float* __restrict__ W2,
                            const float* __restrict__ W3, const float* __restrict__ W4,
                            const float* __restrict__ Wo, unsigned short* __restrict__ ws) {
  int idx = blockIdx.x * blockDim.x + threadIdx.x;
  int stride = gridDim.x * blockDim.x;
  for (int i = idx; i < N_W1; i += stride) ws[i] = f2bf(W1[i]);
  unsigned char* f8 = (unsigned char*)(ws + N_W1);
  for (int i = idx; i < F8_TOT; i += stride) {
    float v;
    if (i < F8_W3)      v = W2[i - F8_W2];
    else if (i < F8_W4) v = W3[i - F8_W3];
    else if (i < F8_WO) v = W4[i - F8_W4];
    else                v = Wo[i - F8_WO];
    f8[i] = f2e4m3(v);
  }
}

// expand 8 spike bits -> 8 fp8 e4m3 bytes (0x00 / 0x38) packed in a long
// (used only to BUILD the LDS LUT).
__device__ __forceinline__ long expand8_f8(unsigned t) {
  unsigned lo = ((t & 0xFu) * 0x204081u) & 0x01010101u;
  unsigned hi = ((t >> 4) * 0x204081u) & 0x01010101u;
  lo *= 0x38u; hi *= 0x38u;
  union { unsigned u[2]; long l; } cv; cv.u[0] = lo; cv.u[1] = hi;
  return cv.l;
}

__global__ __launch_bounds__(256, 4) void snn_fused(
    const float* __restrict__ x,             // [2048][150][20] f32
    const unsigned short* __restrict__ wsb,  // d_ws: bf16 W1 + fp8 W2..Wo
    const float* __restrict__ b1,            // [256] f32
    const float* __restrict__ b2,
    const float* __restrict__ b3,
    const float* __restrict__ b4,
    float* __restrict__ out)                 // [2048][200] f32
{
  __shared__ float sc[SCB];                  // 20480 B: col-major C scratch
  __shared__ unsigned int ubits[2][BITN];    // 15424 B: spike bits, ping-pong
  __shared__ long lut[256];                  //  2048 B: byte -> 8 fp8 spikes
                                             // total 37952 B -> 4 blocks/CU

  const int tid  = threadIdx.x;
  const int lane = tid & 63;
  const int wave = tid >> 6;    // 0..3
  const int c16  = lane & 15;
  const int quad = lane >> 4;
  const int shq  = quad * 8;
  const int bidx = blockIdx.x;
  const int colw = 64 * wave;   // wave owns cols [64w, 64w+64)
  const int cb   = colw + c16;

  const unsigned char* f8 = (const unsigned char*)(wsb + N_W1);
  unsigned short* xa = (unsigned short*)&ubits[1][0];

  auto store_c = [&](f32x4* c) {
    #pragma unroll
    for (int i = 0; i < 4; ++i)
      *(f32x4*)&sc[(cb + 16 * i) * CST + quad * 4] = c[i];
  };

  // fused membrane scan, two-half form; 64 lanes own the wave's 64 cols.
  auto scan_tile = [&](int mt, float& m, unsigned int* wb) {
    const f32x4* vp = (const f32x4*)&sc[(colw + lane) * CST];
    unsigned long long keep = 0ull;
    #pragma unroll
    for (int h = 0; h < 2; ++h) {
      f32x4 v0 = vp[2 * h], v1 = vp[2 * h + 1];
      #pragma unroll
      for (int rr = 0; rr < 8; ++rr) {
        int r = 8 * h + rr;
        int t = mt * 16 + r;
        if (t < T_N) {  // block-uniform
          float inp = (rr < 4) ? v0[rr & 3] : v1[rr & 3];
          float sel = (m > 1.0f) ? (inp - 1.0f) : inp;
          m = 0.9f * m + sel;
          unsigned long long msk = __ballot(m > 1.0f);
          if (lane == r) keep = msk;
        }
      }
    }
    if (lane < 16)
      *(unsigned long long*)&wb[(mt * 16 + lane) * BW + 2 * wave] = keep;
  };

  // ---- init: zero bits buffers, build LUT, stage x as bf16 ----
  for (int i = tid; i < 2 * BITN; i += 256) ((unsigned int*)ubits)[i] = 0;
  lut[tid] = expand8_f8((unsigned)tid);
  __syncthreads();
  {
    const float* xb = x + (size_t)bidx * (T_N * DIN);
    for (int i = tid; i < T_N * DIN; i += 256) {
      int t = i / DIN, j = i - t * DIN;
      xa[t * XAP + j] = f2bf(xb[i]);
    }
  }

  // ---- layer 1 (bf16): x @ W1^T (K=20 pad 32) -> ubits[0]; barrier-free ----
  {
    s16x8 w1f[4];
    #pragma unroll
    for (int i = 0; i < 4; ++i) {
      int n = cb + 16 * i;
      #pragma unroll
      for (int j = 0; j < 8; ++j) {
        int k = shq + j;
        w1f[i][j] = (k < DIN) ? (short)wsb[n * DIN + k] : (short)0;
      }
      asm volatile("" : "+v"(w1f[i]));
    }
    float bc[4];
    #pragma unroll
    for (int i = 0; i < 4; ++i) bc[i] = b1[cb + 16 * i];
    float m = 0.0f;
    __syncthreads();  // xa staged + LUT built
    for (int mt = 0; mt < NMT; ++mt) {
      const s16x8 a1 = *(const s16x8*)&xa[(mt * 16 + c16) * XAP + shq];
      f32x4 c[4];
      #pragma unroll
      for (int i = 0; i < 4; ++i) { f32x4 z = {bc[i], bc[i], bc[i], bc[i]}; c[i] = z; }
      #pragma unroll
      for (int i = 0; i < 4; ++i)
        c[i] = __builtin_amdgcn_mfma_f32_16x16x32_bf16(a1, w1f[i], c[i], 0, 0, 0);
      if (mt > 0) scan_tile(mt - 1, m, ubits[0]);
      store_c(c);
    }
    scan_tile(9, m, ubits[0]);
  }
  __syncthreads();  // bits[0] complete (xa dead from here)

  // ---- layers 2..4 (fp8 weights): barrier-free, bits ping-pong ----
  const float* bsl[3] = {b2, b3, b4};
  const int wofs[3] = {F8_W2, F8_W3, F8_W4};
  for (int l = 0; l < 3; ++l) {
    const unsigned char* wl = f8 + wofs[l];
    const int rp = l & 1, wp = rp ^ 1;
    __builtin_amdgcn_sched_barrier(0);
    long wf[4][8];
    #pragma unroll
    for (int i = 0; i < 4; ++i) {
      int n = cb + 16 * i;
      #pragma unroll
      for (int ks = 0; ks < 8; ++ks) {
        wf[i][ks] = *(const long*)(wl + n * H + ks * 32 + shq);
        asm volatile("" : "+v"(wf[i][ks]));
      }
    }
    __builtin_amdgcn_sched_barrier(0);
    float bc[4];
    #pragma unroll
    for (int i = 0; i < 4; ++i) bc[i] = bsl[l][cb + 16 * i];
    float m = 0.0f;
    for (int mt = 0; mt < NMT; ++mt) {
      const unsigned int* bp = &ubits[rp][(mt * 16 + c16) * BW];
      f32x4 c[4];
      #pragma unroll
      for (int i = 0; i < 4; ++i) { f32x4 z = {bc[i], bc[i], bc[i], bc[i]}; c[i] = z; }
      #pragma unroll
      for (int h = 0; h < 2; ++h) {
        u32x4 rm = *(const u32x4*)(bp + 4 * h);
        #pragma unroll
        for (int kk = 0; kk < 4; ++kk) {
          long a = lut[(rm[kk] >> shq) & 0xFFu];   // LDS LUT expansion
          int ks = 4 * h + kk;
          #pragma unroll
          for (int i = 0; i < 4; ++i)
            c[i] = __builtin_amdgcn_mfma_f32_16x16x32_fp8_fp8(a, wf[i][ks], c[i], 0, 0, 0);
        }
      }
      if (mt > 0) scan_tile(mt - 1, m, ubits[wp]);
      store_c(c);
    }
    scan_tile(9, m, ubits[wp]);
    __syncthreads();  // bits[wp] complete
  }

  // ---- output layer (fp8, reads ubits[1]): GEMM + mo-scan + softmax ----
  {
    __builtin_amdgcn_sched_barrier(0);
    long wo[4][8];
    #pragma unroll
    for (int i = 0; i < 4; ++i) {
      int n = cb + 16 * i;
      bool valid = (n < NOUT);
      #pragma unroll
      for (int ks = 0; ks < 8; ++ks) {
        wo[i][ks] = valid ? *(const long*)(f8 + F8_WO + n * H + ks * 32 + shq) : 0L;
        asm volatile("" : "+v"(wo[i][ks]));
      }
    }
    __builtin_amdgcn_sched_barrier(0);

    float mo = 0.0f;
    float a0 = 0.f, a1 = 0.f, a2 = 0.f, a3 = 0.f;

    auto moscan = [&](int mt) {
      if (tid < 208) {
        f32x4* vp = (f32x4*)&sc[tid * CST];
        #pragma unroll
        for (int h = 0; h < 2; ++h) {
          f32x4 v0 = vp[2 * h], v1 = vp[2 * h + 1];
          #pragma unroll
          for (int rr = 0; rr < 8; ++rr) {
            int r = 8 * h + rr;
            int t = mt * 16 + r;
            if (t < T_N) {
              float inp = (rr < 4) ? v0[rr & 3] : v1[rr & 3];
              float reset = (mo > 1.0f) ? 1.0f : 0.0f;
              mo = 0.9f * mo + inp - reset;
              if (rr < 4) v0[rr & 3] = mo; else v1[rr & 3] = mo;
            }
          }
          vp[2 * h] = v0; vp[2 * h + 1] = v1;
        }
      }
    };
    auto softmax_t = [&](int mt) {
      #pragma unroll
      for (int rr = 0; rr < 4; ++rr) {
        int r = 4 * wave + rr;
        int t = mt * 16 + r;
        if (t > 50 && t < T_N) {        // wave-uniform
          const float* p = &sc[r];
          float v0 = p[lane * CST];
          float v1 = p[(64 + lane) * CST];
          float v2 = p[(128 + lane) * CST];
          bool has3 = (lane < 8);
          float v3 = has3 ? p[(192 + lane) * CST] : -INFINITY;
          float mx = fmaxf(fmaxf(v0, v1), fmaxf(v2, v3));
          #pragma unroll
          for (int d = 32; d >= 1; d >>= 1) mx = fmaxf(mx, __shfl_xor(mx, d));
          float e0 = __expf(v0 - mx), e1 = __expf(v1 - mx), e2 = __expf(v2 - mx);
          float e3 = has3 ? __expf(v3 - mx) : 0.0f;
          float s = e0 + e1 + e2 + e3;
          #pragma unroll
          for (int d = 32; d >= 1; d >>= 1) s += __shfl_xor(s, d);
          float inv = 1.0f / s;
          a0 += e0 * inv; a1 += e1 * inv; a2 += e2 * inv; a3 += e3 * inv;
        }
      }
    };

    for (int mt = 0; mt < NMT; ++mt) {
      const unsigned int* bp = &ubits[1][(mt * 16 + c16) * BW];
      f32x4 c[4];
      #pragma unroll
      for (int i = 0; i < 4; ++i) { f32x4 z = {0.f, 0.f, 0.f, 0.f}; c[i] = z; }
      #pragma unroll
      for (int h = 0; h < 2; ++h) {
        u32x4 rm = *(const u32x4*)(bp + 4 * h);
        #pragma unroll
        for (int kk = 0; kk < 4; ++kk) {
          long a = lut[(rm[kk] >> shq) & 0xFFu];   // LDS LUT expansion
          int ks = 4 * h + kk;
          #pragma unroll
          for (int i = 0; i < 4; ++i)
            c[i] = __builtin_amdgcn_mfma_f32_16x16x32_fp8_fp8(a, wo[i][ks], c[i], 0, 0, 0);
        }
      }
      __syncthreads();              // prior softmax done reading sc
      store_c(c);
      moscan(mt);                   // wave-local after wave-local store
      __syncthreads();              // membranes visible to all waves
      softmax_t(mt);
    }
    __syncthreads();

    // merge 4 per-wave accumulators via sc, store f32
    sc[wave * 260 + lane]       = a0;
    sc[wave * 260 + 64 + lane]  = a1;
    sc[wave * 260 + 128 + lane] = a2;
    if (lane < 8) sc[wave * 260 + 192 + lane] = a3;
    __syncthreads();
    if (tid < NOUT) {
      float v = sc[tid] + sc[260 + tid] + sc[520 + tid] + sc[780 + tid];
      out[(size_t)bidx * NOUT + tid] = v;
    }
  }
}

extern "C" void kernel_launch(void* const* d_in, const int* in_sizes, int n_in,
                              void* d_out, int out_size, void* d_ws, size_t ws_size,
                              hipStream_t stream) {
  (void)in_sizes; (void)n_in; (void)ws_size; (void)out_size;
  unsigned short* wsb = (unsigned short*)d_ws;
  cvt_weights<<<256, 256, 0, stream>>>(
      (const float*)d_in[1], (const float*)d_in[3], (const float*)d_in[5],
      (const float*)d_in[7], (const float*)d_in[9], wsb);
  snn_fused<<<2048, 256, 0, stream>>>(
      (const float*)d_in[0], wsb,
      (const float*)d_in[2], (const float*)d_in[4],
      (const float*)d_in[6], (const float*)d_in[8],
      (float*)d_out);
}